// Round 8
// baseline (1077.933 us; speedup 1.0000x reference)
//
#include <hip/hip_runtime.h>

// Encoder: fused pre (embed + weight-prep + Whh-quant + mailbox zero, one launch)
//          -> fused input GEMM (sen+tgt one launch; bf16 MFMA, 128-row m-tiles, B panel
//             staged once in padded LDS, barrier-free K-loop; 16-unit x 4-gate tiles =>
//             contiguous 8B gate-interleaved stores into TIME-MAJOR G [t][b][4H])
//          -> LSTM scan, 48 WGs x 512 thr:
//             sen dirs UNIT-SPLIT 2-way: WG(dir,chunk,half) owns 128 units x 16 batches,
//             8 waves @ 2 waves/SIMD over 32 CUs (R7 was 16 CUs @ 79% active VALUBusy =
//             issue-bound; per-wave work unchanged, per-SIMD issue halves). Halves swap
//             h i8 slices via agent-scope atomics (XCD L2s not coherent): relaxed byte
//             stores -> barrier(vmcnt drain) -> release flag; partner spins acquire,
//             reads its 2 missing A-frags as agent u64 loads. Parity double-buffered
//             mailbox (flag-ordered +-1-step lockstep => no overwrite race). Deadlock-
//             free by capacity: 48 WGs <= 256 CUs, all resident.
//             tgt dirs (T=8) unsplit: 8 waves x 32 units, overlap sen for free.
//          -> co-attention + output head (reads time-major H).
// Sizes: V=100000 E=300 H=256 OUT=3 B=128 LS=128 LT=8

typedef unsigned short u16;
typedef unsigned int u32;
typedef unsigned long long u64;
typedef float f32x4 __attribute__((ext_vector_type(4)));
typedef int   i32x4 __attribute__((ext_vector_type(4)));
typedef short bf16x8 __attribute__((ext_vector_type(8)));
typedef short s16x4 __attribute__((ext_vector_type(4)));
typedef unsigned short u16x4 __attribute__((ext_vector_type(4)));

#define KP 320   // E=300 padded to mult of 32
#define KPL 328  // LDS leading dim (u16): 656B row stride, 16B aligned
#define FH 1024  // 4*H
#define HH 256   // H
#define L2E 1.4426950408889634f

struct Ptr4 { const float* p[4]; };

static __device__ __forceinline__ u16 f2bf(float f) {
    unsigned int u = __float_as_uint(f);
    u += 0x7FFFu + ((u >> 16) & 1u);          // RNE
    return (u16)(u >> 16);
}
static __device__ __forceinline__ float bf2f(u16 s) {
    return __uint_as_float((unsigned int)s << 16);
}
// pre-scaled activations: input already multiplied by log2e (sigm2) / 2*log2e (tanh2)
static __device__ __forceinline__ float sigm2(float x) {   // sigmoid(raw), x = raw*log2e
    return __builtin_amdgcn_rcpf(1.0f + __builtin_amdgcn_exp2f(-x));
}
static __device__ __forceinline__ float tanh2(float x) {   // tanh(raw), x = raw*2*log2e
    return 1.0f - 2.0f * __builtin_amdgcn_rcpf(1.0f + __builtin_amdgcn_exp2f(x));
}

// ---------------------------------------------------------------- fused pre
// blocks [0,17408): embed   [17408,22528): Wih/bias prep   [22528,23552): Whh quant
// [23552,23584): zero h-mailbox   23584: zero progress flags.
__global__ __launch_bounds__(256) void pre_kernel(
    const int* __restrict__ sen, const int* __restrict__ tgt,
    const float* __restrict__ emb, Ptr4 Wih, Ptr4 Whh, Ptr4 bih, Ptr4 bhh,
    u16* __restrict__ Xs, u16* __restrict__ Xt,
    u16* __restrict__ WihB, float* __restrict__ biasB,
    char* __restrict__ Wq, float* __restrict__ wdq,
    char* __restrict__ hx, u32* __restrict__ prog)
{
    int bid = blockIdx.x, tid = threadIdx.x;
    if (bid < 17408) {                       // ---- embedding
        int row = bid;
        int tok; u16* dst;
        if (row < 16384) { tok = sen[row]; dst = Xs + (size_t)row * KP; }
        else             { tok = tgt[row - 16384]; dst = Xt + (size_t)(row - 16384) * KP; }
        const float* src = emb + (size_t)tok * 300;
        for (int k = tid; k < KP; k += 256) {
            float v = (k < 300 && tok != 0) ? src[k] : 0.0f;   // padding_idx=0
            dst[k] = f2bf(v);
        }
    } else if (bid < 22528) {                // ---- Wih -> bf16 (prescaled), bias fold
        int local = bid - 17408;
        int dir = local / 1280, blk = local - dir * 1280;
        int idx = blk * 256 + tid;
        if (idx < FH * KP) {
            int row = idx / KP, k = idx - row * KP;
            float gsc = ((row >> 8) == 2) ? 2.0f * L2E : L2E;
            WihB[(size_t)dir * FH * KP + idx] =
                (k < 300) ? f2bf(Wih.p[dir][row * 300 + k] * gsc) : (u16)0;
        }
        if (idx < FH) {
            float gsc = ((idx >> 8) == 2) ? 2.0f * L2E : L2E;
            biasB[dir * FH + idx] = (bih.p[dir][idx] + bhh.p[dir][idx]) * gsc;
        }
    } else if (bid < 23552) {                // ---- Whh -> i8 row-scaled (prescaled wdq)
        int local = bid - 22528;
        int w = tid >> 6, lane = tid & 63;
        int pair = local * 4 + w;
        int dir = pair >> 10, row = pair & 1023;
        const float* src = Whh.p[dir] + (size_t)row * HH;
        float m = 0.0f;
        for (int k = lane; k < HH; k += 64) m = fmaxf(m, fabsf(src[k]));
        for (int off = 32; off; off >>= 1) m = fmaxf(m, __shfl_down(m, off));
        m = __shfl(m, 0);
        float qs = (m > 0.0f) ? 127.0f / m : 0.0f;
        char* dst = Wq + (size_t)dir * FH * HH + (size_t)row * HH;
        for (int k = lane; k < HH; k += 64) dst[k] = (char)(int)rintf(src[k] * qs);
        if (lane == 0) {
            float gsc = ((row >> 8) == 2) ? 2.0f * L2E : L2E;
            wdq[dir * FH + row] = (m > 0.0f) ? m / (127.0f * 127.0f) * gsc : 0.0f;
        }
    } else if (bid < 23584) {                // ---- zero h-mailbox (stale across launches)
        int local = bid - 23552;
        f32x4 z = {};
        *(f32x4*)(hx + (size_t)local * 4096 + tid * 16) = z;
    } else {                                 // ---- zero progress flags
        if (tid < 32) prog[tid] = 0;
    }
}

// ---------------------------------------------------------------- fused input GEMM
// bid<4096: sen (M=16384, dirs 0,1, T=128).  bid>=4096: tgt (M=1024, dirs 2,3, T=8).
// 128-row m-tile x {16 units x 4 gates} per 256-thr block; 64-row B panel staged once
// in padded LDS; barrier-free K-loop; XCD swizzle for L2 locality. Epilogue: one 8B
// u16x4 store per (sub,reg) into TIME-MAJOR G [t][b][unit*4+gate].
__global__ __launch_bounds__(256) void input_gemm_kernel(
    const u16* __restrict__ Xs, const u16* __restrict__ Xt,
    const u16* __restrict__ WihB, const float* __restrict__ biasB,
    u16* __restrict__ Gs, u16* __restrict__ Gt)
{
    __shared__ u16 Bs[64][KPL];

    int bid = blockIdx.x;
    const u16* X; const u16* W; const float* bias; u16* G;
    int lbid, nwg, tsh;
    if (bid < 4096) { lbid = bid;        nwg = 4096; tsh = 7;
                      X = Xs; W = WihB;                         bias = biasB;          G = Gs; }
    else            { lbid = bid - 4096; nwg = 256;  tsh = 3;
                      X = Xt; W = WihB + (size_t)2 * FH * KP;   bias = biasB + 2 * FH; G = Gt; }

    int cpx = nwg >> 3;
    int wid = (lbid & 7) * cpx + (lbid >> 3);
    int nblk = wid & 31;                       // 2 dirs x 16 unit-tiles
    int mblk = wid >> 5;
    int dirb = nblk >> 4;
    int u0   = (nblk & 15) * 16;
    size_t dirStride = (size_t)(tsh == 7 ? 16384 : 1024) * FH;

    int tid = threadIdx.x;
    int wave = tid >> 6, lane = tid & 63;
    int r = lane & 15, quad = lane >> 4;
    int m0 = mblk * 128 + wave * 32;           // wave covers 32 m-rows (2 subtiles)

    // ---- stage B panel: rows j*16+rr = W[dirb*1024 + j*256 + u0 + rr], full K=320
#pragma unroll
    for (int it = 0; it < 10; ++it) {
        int idx = it * 256 + tid;
        int row = idx / 40, cc = idx - row * 40;
        int j = row >> 4, rr = row & 15;
        bf16x8 v = *(const bf16x8*)(W + ((size_t)dirb * FH + j * 256 + u0 + rr) * KP + cc * 8);
        *(bf16x8*)&Bs[row][cc * 8] = v;
    }
    __syncthreads();

    // ---- barrier-free K loop, 2 m-subtiles share each B fragment
    const u16* xr = X + (size_t)(m0 + r) * KP + quad * 8;
    f32x4 acc[2][4] = {};
#pragma unroll
    for (int k0 = 0; k0 < KP; k0 += 32) {
        bf16x8 a0 = *(const bf16x8*)(xr + k0);
        bf16x8 a1 = *(const bf16x8*)(xr + 16 * KP + k0);
#pragma unroll
        for (int j = 0; j < 4; ++j) {
            bf16x8 b = *(const bf16x8*)&Bs[j * 16 + r][k0 + quad * 8];
            acc[0][j] = __builtin_amdgcn_mfma_f32_16x16x32_bf16(a0, b, acc[0][j], 0, 0, 0);
            acc[1][j] = __builtin_amdgcn_mfma_f32_16x16x32_bf16(a1, b, acc[1][j], 0, 0, 0);
        }
    }

    // ---- epilogue: bias + bf16; one 8B store per (sub,reg) into time-major G
#pragma unroll
    for (int sub = 0; sub < 2; ++sub)
#pragma unroll
        for (int reg = 0; reg < 4; ++reg) {
            int m = m0 + sub * 16 + quad * 4 + reg;
            int b = m >> tsh, t = m & ((1 << tsh) - 1);
            int unit = u0 + r;
            u16x4 ov;
#pragma unroll
            for (int j = 0; j < 4; ++j)
                ov[j] = f2bf(acc[sub][j][reg] + bias[dirb * FH + j * 256 + unit]);
            *(u16x4*)(G + (size_t)dirb * dirStride + ((size_t)t * 128 + b) * FH + unit * 4) = ov;
        }
}

// ---------------------------------------------------------------- LSTM scan
// 48 WGs x 512 thr (8 waves; launch_bounds(512,2) => 2 waves/SIMD, 256-reg cap).
// bx<32: sen, bx = dir*16 + chunk*2 + half. bx>=32: tgt, unsplit.
// Sen WG: 16 batches x 128 units (its half); wave w owns units half*128+w*16..+16 x 4
// gates (Bq 64 regs). Per step: gv prefetch + Hout(h(s-1)) store at top (retire under
// compute, R3); own A-frags from LDS; spin acquire on partner flag >= s; partner A-frags
// = 4 agent u64 loads from mailbox buf[(s-1)&1]; 16 MFMA (own k-slices first); gates;
// h -> own LDS + 4 agent byte stores to mailbox buf[s&1]; barrier (drains stores);
// lane 0 publishes flag s+1 (release). Mailbox parity safe: partner can only reuse a
// parity buffer after seeing MY flag, which follows MY reads of it.
__global__ __launch_bounds__(512, 2) void lstm_scan_kernel(
    const char*  __restrict__ WqB,   // [4][1024][256] i8
    const float* __restrict__ wdq,   // [4][1024] dequant scales (prescaled)
    const u16*   __restrict__ Gs,    // [2][128t][128b][1024] bf16
    const u16*   __restrict__ Gt,    // [2][8t][128b][1024] bf16
    float* __restrict__ senH,        // [128t][128b][512]  TIME-MAJOR
    float* __restrict__ tgtH,        // [8t][128b][512]    TIME-MAJOR
    char*  __restrict__ hx,          // [32 pair-half][2 parity][16][128] i8 mailbox
    u32*   __restrict__ prog)        // [32] steps published per sen WG
{
    const int bx  = blockIdx.x;
    const int tid = threadIdx.x;
    const int w    = tid >> 6, lane = tid & 63;
    const int r    = lane & 15, quad = lane >> 4;

    __shared__ __align__(16) char hb[2][16][272];

    for (int i = tid; i < 2 * 16 * 272; i += 512) (&hb[0][0][0])[i] = 0;
    __syncthreads();

    if (bx < 32) {
        // ======================= sen: unit-split halves =======================
        const int dir   = bx >> 4;          // 0,1
        const int chunk = (bx >> 1) & 7;
        const int ph    = bx & 1;           // which unit half this WG owns
        const int b0    = chunk << 4;
        const int rev   = dir & 1;
        const int T     = 128;

        const char* Wq = WqB + (size_t)dir * FH * HH;
        const u16*  G  = Gs + (size_t)dir * 16384 * FH;
        const int hofs = rev ? 256 : 0;
        const int uloc = w * 16 + r;        // 0..127 within half
        const int ug   = ph * 128 + uloc;   // global unit

        const int pairI = dir * 8 + chunk;
        char* sliceW = hx + ((size_t)(pairI * 2 + ph) * 2) * 2048;
        char* sliceR = hx + ((size_t)(pairI * 2 + (1 - ph)) * 2) * 2048;
        u32* progMe = prog + pairI * 2 + ph;
        u32* progP  = prog + pairI * 2 + (1 - ph);

        // Bq[g][j]: j=0,1 own k-slices (kt=ph*2+j), j=2,3 partner ((1-ph)*2+(j-2)).
        // Index arithmetic at LOAD time only => all register-array indices static.
        i32x4 Bq[4][4];
        float dqv[4];
#pragma unroll
        for (int g = 0; g < 4; ++g) {
            int row = g * 256 + ug;
            dqv[g] = wdq[dir * FH + row];
#pragma unroll
            for (int j = 0; j < 4; ++j) {
                int kt = (j < 2) ? (ph * 2 + j) : ((1 - ph) * 2 + (j - 2));
                Bq[g][j] = *(const i32x4*)(Wq + ((size_t)row << 8) + kt * 64 + quad * 16);
            }
        }

        float c[4] = {}, hreg[4] = {};

        const int t0 = rev ? (T - 1) : 0;
        const ptrdiff_t gstep = rev ? -(ptrdiff_t)(128 * FH) : (ptrdiff_t)(128 * FH);
        const ptrdiff_t hstep = rev ? -(ptrdiff_t)(128 * 512) : (ptrdiff_t)(128 * 512);
        const u16* gp0 = G + ((size_t)t0 * 128 + b0 + quad * 4) * FH + ug * 4;
        const u16* gp2 = gp0 + 2 * (size_t)FH;
        float* hp0 = senH + ((size_t)t0 * 128 + b0 + quad * 4) * 512 + hofs + ug;
        float* hp2 = hp0 + 2 * 512;

        s16x4 gvA[4], gvB[4];
        gvA[0] = *(const s16x4*)(gp0);
        gvA[1] = *(const s16x4*)(gp0 + FH);
        gvA[2] = *(const s16x4*)(gp2);
        gvA[3] = *(const s16x4*)(gp2 + FH);
        gp0 += gstep; gp2 += gstep;

        auto body = [&](int cur, s16x4 (&gvU)[4], s16x4 (&gvP)[4], int s, int doStore) {
            gvP[0] = *(const s16x4*)(gp0);
            gvP[1] = *(const s16x4*)(gp0 + FH);
            gvP[2] = *(const s16x4*)(gp2);
            gvP[3] = *(const s16x4*)(gp2 + FH);
            gp0 += gstep; gp2 += gstep;
            if (doStore) {
                hp0[0] = hreg[0]; hp0[512] = hreg[1];
                hp2[0] = hreg[2]; hp2[512] = hreg[3];
                hp0 += hstep; hp2 += hstep;
            }

            // own A-frags (LDS, complete since last barrier)
            i32x4 aO0 = *(const i32x4*)&hb[cur][r][quad * 16];
            i32x4 aO1 = *(const i32x4*)&hb[cur][r][64 + quad * 16];

            // partner h(s-1): spin acquire, then agent-coherent loads
            if (s > 0)
                while (__hip_atomic_load(progP, __ATOMIC_ACQUIRE,
                                         __HIP_MEMORY_SCOPE_AGENT) < (u32)s)
                    __builtin_amdgcn_s_sleep(1);
            char* sr = sliceR + (cur ^ 1) * 2048 + r * 128 + quad * 16;
            u64 p00 = __hip_atomic_load((u64*)(sr),      __ATOMIC_RELAXED, __HIP_MEMORY_SCOPE_AGENT);
            u64 p01 = __hip_atomic_load((u64*)(sr + 8),  __ATOMIC_RELAXED, __HIP_MEMORY_SCOPE_AGENT);
            u64 p10 = __hip_atomic_load((u64*)(sr + 64), __ATOMIC_RELAXED, __HIP_MEMORY_SCOPE_AGENT);
            u64 p11 = __hip_atomic_load((u64*)(sr + 72), __ATOMIC_RELAXED, __HIP_MEMORY_SCOPE_AGENT);
            i32x4 aP0, aP1;
            ((u64*)&aP0)[0] = p00; ((u64*)&aP0)[1] = p01;
            ((u64*)&aP1)[0] = p10; ((u64*)&aP1)[1] = p11;

            i32x4 acc[4] = {};
#pragma unroll
            for (int g = 0; g < 4; ++g) {
                acc[g] = __builtin_amdgcn_mfma_i32_16x16x64_i8(aO0, Bq[g][0], acc[g], 0, 0, 0);
                acc[g] = __builtin_amdgcn_mfma_i32_16x16x64_i8(aO1, Bq[g][1], acc[g], 0, 0, 0);
                acc[g] = __builtin_amdgcn_mfma_i32_16x16x64_i8(aP0, Bq[g][2], acc[g], 0, 0, 0);
                acc[g] = __builtin_amdgcn_mfma_i32_16x16x64_i8(aP1, Bq[g][3], acc[g], 0, 0, 0);
            }

            char* sw = sliceW + cur * 2048 + uloc;
#pragma unroll
            for (int reg = 0; reg < 4; ++reg) {
                int bb = quad * 4 + reg;
                float pi = (float)acc[0][reg] * dqv[0] + bf2f((u16)gvU[reg].x);
                float pf = (float)acc[1][reg] * dqv[1] + bf2f((u16)gvU[reg].y);
                float pg = (float)acc[2][reg] * dqv[2] + bf2f((u16)gvU[reg].z);
                float po = (float)acc[3][reg] * dqv[3] + bf2f((u16)gvU[reg].w);
                float ig = sigm2(pi), fg = sigm2(pf), gg = tanh2(pg), og = sigm2(po);
                float cn = fg * c[reg] + ig * gg;
                c[reg] = cn;
                float hn = og * tanh2(cn * (2.0f * L2E));
                char q = (char)(int)rintf(hn * 127.0f);
                hb[cur ^ 1][bb][uloc] = q;
                __hip_atomic_store(sw + bb * 128, q, __ATOMIC_RELAXED,
                                   __HIP_MEMORY_SCOPE_AGENT);
                hreg[reg] = hn;
            }
            __syncthreads();   // h(s) in LDS; mailbox stores drained (vmcnt) here
            if (tid == 0)
                __hip_atomic_store(progMe, (u32)(s + 1), __ATOMIC_RELEASE,
                                   __HIP_MEMORY_SCOPE_AGENT);
        };

        for (int s2 = 0; s2 < T; s2 += 2) {
            body(0, gvA, gvB, s2, s2 > 0);   // even: reads hb[0], writes hb[1]
            body(1, gvB, gvA, s2 + 1, 1);    // odd:  reads hb[1], writes hb[0]
        }
        // epilogue: store h(T-1)
        hp0[0] = hreg[0]; hp0[512] = hreg[1];
        hp2[0] = hreg[2]; hp2[512] = hreg[3];
    } else {
        // ======================= tgt: T=8, unsplit =======================
        const int lb    = bx - 32;
        const int dir   = 2 + (lb >> 3);
        const int chunk = lb & 7;
        const int b0    = chunk << 4;
        const int rev   = dir & 1;

        const char* Wq = WqB + (size_t)dir * FH * HH;
        const u16*  G  = Gt + (size_t)(dir - 2) * 1024 * FH;
        const int hofs = rev ? 256 : 0;

        // wave owns 32 units (2 subtiles of 16) x 4 gates: Bq2 = 128 regs
        i32x4 Bq2[2][4][4];
        float dqv2[2][4];
#pragma unroll
        for (int su = 0; su < 2; ++su)
#pragma unroll
            for (int g = 0; g < 4; ++g) {
                int row = g * 256 + w * 32 + su * 16 + r;
                dqv2[su][g] = wdq[dir * FH + row];
#pragma unroll
                for (int kt = 0; kt < 4; ++kt)
                    Bq2[su][g][kt] = *(const i32x4*)(Wq + ((size_t)row << 8) + kt * 64 + quad * 16);
            }

        float c2[2][4] = {};
        for (int s = 0; s < 8; ++s) {
            const int t = rev ? (7 - s) : s;
            const int cur = s & 1;
            s16x4 gv[2][4];
#pragma unroll
            for (int su = 0; su < 2; ++su)
#pragma unroll
                for (int reg = 0; reg < 4; ++reg)
                    gv[su][reg] = *(const s16x4*)(G + ((size_t)t * 128 + b0 + quad * 4 + reg) * FH
                                                  + (w * 32 + su * 16 + r) * 4);
            i32x4 af[4];
#pragma unroll
            for (int kt = 0; kt < 4; ++kt)
                af[kt] = *(const i32x4*)&hb[cur][r][kt * 64 + quad * 16];

            i32x4 acc[2][4] = {};
#pragma unroll
            for (int su = 0; su < 2; ++su)
#pragma unroll
                for (int g = 0; g < 4; ++g)
#pragma unroll
                    for (int kt = 0; kt < 4; ++kt)
                        acc[su][g] = __builtin_amdgcn_mfma_i32_16x16x64_i8(
                            af[kt], Bq2[su][g][kt], acc[su][g], 0, 0, 0);

#pragma unroll
            for (int su = 0; su < 2; ++su)
#pragma unroll
                for (int reg = 0; reg < 4; ++reg) {
                    int bb = quad * 4 + reg;
                    int u = w * 32 + su * 16 + r;
                    float pi = (float)acc[su][0][reg] * dqv2[su][0] + bf2f((u16)gv[su][reg].x);
                    float pf = (float)acc[su][1][reg] * dqv2[su][1] + bf2f((u16)gv[su][reg].y);
                    float pg = (float)acc[su][2][reg] * dqv2[su][2] + bf2f((u16)gv[su][reg].z);
                    float po = (float)acc[su][3][reg] * dqv2[su][3] + bf2f((u16)gv[su][reg].w);
                    float ig = sigm2(pi), fg = sigm2(pf), gg = tanh2(pg), og = sigm2(po);
                    float cn = fg * c2[su][reg] + ig * gg;
                    c2[su][reg] = cn;
                    float hn = og * tanh2(cn * (2.0f * L2E));
                    hb[cur ^ 1][bb][u] = (char)(int)rintf(hn * 127.0f);
                    tgtH[((size_t)t * 128 + b0 + bb) * 512 + hofs + u] = hn;
                }
            __syncthreads();
        }
    }
}

// ---------------------------------------------------------------- attention + head
// Reads TIME-MAJOR senH/tgtH: row (b,s) lives at ((s*128)+b)*512.
__global__ __launch_bounds__(256) void attn_out_kernel(
    const float* __restrict__ senH, const float* __restrict__ tgtH,
    const float* __restrict__ Wout, const float* __restrict__ bout,
    float* __restrict__ out)
{
    int b = blockIdx.x, tid = threadIdx.x;
    __shared__ float tg[8][512];
    __shared__ float Am[128][9];
    __shared__ float rowm[128][9];
    __shared__ float mcol[8], csum[8], rvec[8], attn[128], score[512], lg[3];

    for (int i = tid; i < 4096; i += 256) {
        int t = i >> 9, h = i & 511;
        tg[t][h] = tgtH[((size_t)t * 128 + b) * 512 + h];
    }
    __syncthreads();

    {   // A[s][t] = sen_h[b,s,:] . tgt_h[b,t,:]
        int s = tid >> 1, t0 = (tid & 1) * 4;
        const float* sr = senH + ((size_t)s * 128 + b) * 512;
        float d0 = 0, d1 = 0, d2 = 0, d3 = 0;
        for (int h = 0; h < 512; ++h) {
            float x = sr[h];
            d0 += x * tg[t0 + 0][h]; d1 += x * tg[t0 + 1][h];
            d2 += x * tg[t0 + 2][h]; d3 += x * tg[t0 + 3][h];
        }
        Am[s][t0 + 0] = d0; Am[s][t0 + 1] = d1; Am[s][t0 + 2] = d2; Am[s][t0 + 3] = d3;
    }
    __syncthreads();

    if (tid < 8) {  // col-softmax stats over s, per t
        float m = -1e30f;
        for (int s = 0; s < 128; ++s) m = fmaxf(m, Am[s][tid]);
        float sum = 0;
        for (int s = 0; s < 128; ++s) sum += __expf(Am[s][tid] - m);
        mcol[tid] = m; csum[tid] = sum;
    }
    if (tid >= 64 && tid < 192) {  // row softmax per s
        int s = tid - 64;
        float m = -1e30f;
        for (int t = 0; t < 8; ++t) m = fmaxf(m, Am[s][t]);
        float e[8], sum = 0;
        for (int t = 0; t < 8; ++t) { e[t] = __expf(Am[s][t] - m); sum += e[t]; }
        float inv = __builtin_amdgcn_rcpf(sum);
        for (int t = 0; t < 8; ++t) rowm[s][t] = e[t] * inv;
    }
    __syncthreads();
    if (tid < 8) {
        float sum = 0;
        for (int s = 0; s < 128; ++s) sum += rowm[s][tid];
        rvec[tid] = sum * (1.0f / 128.0f);
    }
    __syncthreads();
    if (tid < 128) {
        float a = 0;
        for (int t = 0; t < 8; ++t)
            a += __expf(Am[tid][t] - mcol[t]) / csum[t] * rvec[t];
        attn[tid] = a;
    }
    __syncthreads();
    for (int h = tid; h < 512; h += 256) {
        float acc = 0;
        const float* sp = senH + b * 512 + h;
        for (int s = 0; s < 128; ++s) acc += attn[s] * sp[(size_t)s * 128 * 512];
        score[h] = acc;
    }
    __syncthreads();
    if (tid < 3) {
        float acc = bout[tid];
        const float* wr = Wout + tid * 512;
        for (int h = 0; h < 512; ++h) acc += score[h] * wr[h];
        lg[tid] = acc;
    }
    __syncthreads();
    if (tid == 0) {
        float m = fmaxf(lg[0], fmaxf(lg[1], lg[2]));
        float e0 = __expf(lg[0] - m), e1 = __expf(lg[1] - m), e2 = __expf(lg[2] - m);
        float inv = 1.0f / (e0 + e1 + e2);
        out[b * 3 + 0] = e0 * inv; out[b * 3 + 1] = e1 * inv; out[b * 3 + 2] = e2 * inv;
    }
}

// ---------------------------------------------------------------- launch
extern "C" void kernel_launch(void* const* d_in, const int* in_sizes, int n_in,
                              void* d_out, int out_size, void* d_ws, size_t ws_size,
                              hipStream_t stream)
{
    const int*   sen = (const int*)d_in[0];
    const int*   tgt = (const int*)d_in[1];
    const float* emb = (const float*)d_in[2];
    Ptr4 Wih = {{(const float*)d_in[3],  (const float*)d_in[7],
                 (const float*)d_in[11], (const float*)d_in[15]}};
    Ptr4 Whh = {{(const float*)d_in[4],  (const float*)d_in[8],
                 (const float*)d_in[12], (const float*)d_in[16]}};
    Ptr4 bih = {{(const float*)d_in[5],  (const float*)d_in[9],
                 (const float*)d_in[13], (const float*)d_in[17]}};
    Ptr4 bhh = {{(const float*)d_in[6],  (const float*)d_in[10],
                 (const float*)d_in[14], (const float*)d_in[18]}};
    const float* Wout = (const float*)d_in[19];
    const float* bout = (const float*)d_in[20];
    float* out = (float*)d_out;

    char* ws = (char*)d_ws;
    size_t off = 0;
    auto alloc = [&](size_t bytes) -> void* {
        void* p = ws + off; off += (bytes + 255) & ~(size_t)255; return p;
    };
    u16*   Xs    = (u16*)alloc((size_t)16384 * KP * 2);
    u16*   Xt    = (u16*)alloc((size_t)1024 * KP * 2);
    u16*   WihB  = (u16*)alloc((size_t)4 * FH * KP * 2);
    char*  WqB   = (char*)alloc((size_t)4 * FH * HH);
    float* wdq   = (float*)alloc((size_t)4 * FH * 4);
    float* biasB = (float*)alloc((size_t)4 * FH * 4);
    u16*   Gs    = (u16*)alloc((size_t)2 * 16384 * FH * 2);
    u16*   Gt    = (u16*)alloc((size_t)2 * 1024 * FH * 2);
    float* senH  = (float*)alloc((size_t)128 * 128 * 512 * 4);
    float* tgtH  = (float*)alloc((size_t)128 * 8 * 512 * 4);
    char*  hx    = (char*)alloc((size_t)131072);   // h mailbox: 32 WGs x 2 parity x 2KB
    u32*   prog  = (u32*)alloc((size_t)128);       // 32 progress flags
    (void)ws_size; (void)in_sizes; (void)n_in; (void)out_size;

    pre_kernel<<<23585, 256, 0, stream>>>(sen, tgt, emb, Wih, Whh, bih, bhh,
                                          Xs, Xt, WihB, biasB, WqB, wdq, hx, prog);
    input_gemm_kernel<<<4352, 256, 0, stream>>>(Xs, Xt, WihB, biasB, Gs, Gt);
    lstm_scan_kernel<<<48, 512, 0, stream>>>(WqB, wdq, Gs, Gt, senH, tgtH, hx, prog);
    attn_out_kernel<<<128, 256, 0, stream>>>(senH, tgtH, Wout, bout, out);
}